// Round 10
// baseline (99.544 us; speedup 1.0000x reference)
//
#include <hip/hip_runtime.h>

// B=32, T_IN=12, H=64, W=64, C_IN=4, T_OUT=12, C_OUT=4, O=48, K=8, S=4
// NH=NW=15, L=225. DEC_K=25, p=12 -> trend[t] = A + t*D (affine in t).
//
// GEMM per class: W_cls[192 x 64] (A-op) . X[64 x pixels] (B-op).
// k: 0..47 w_s(t=k>>2,cin=k&3); 48..51 W0[cin]; 52..55 W1[cin]; 56 bias; pad 0.
// A-frag row m16 = c*4 + combo r (di=r>>1, dj=r&1, s=(rh+4di)*8+(rw+4dj)).
// D: row = quad*4+reg -> (c=quad, combo=reg); col = nlane -> pixel.
//
// Main block = (b, rh, w-half, to-half): 16 contiguous rows x 32 cols, 6 of 12
// output timesteps. toh split doubles blocks/CU (LDS 69632 B -> 2 resident) =
// 16 waves/CU for latency hiding; duplicated x read is L3-hot (x=25MB < LLC).
// Weight-fragment loads hoisted above phase 1 so both streams are in flight.

typedef _Float16 h2 __attribute__((ext_vector_type(2)));
typedef _Float16 f16x8 __attribute__((ext_vector_type(8)));
typedef float f32x4 __attribute__((ext_vector_type(4)));
union F2H8 { struct { float2 lo, hi; } f; f16x8 h8; };
union F4H8 { float4 f4; f16x8 h8; };
union HU { _Float16 h; unsigned short u; };

// ---- pack: 192 blocks (cls*12+to) x 256 threads.
__global__ __launch_bounds__(256) void pack_frags(const float* __restrict__ w_s,
                                                  const float* __restrict__ b_s,
                                                  const float* __restrict__ w_t,
                                                  const float* __restrict__ b_t,
                                                  uint2* __restrict__ PWF) {
    __shared__ float W01[2][16][4];
    int blk = blockIdx.x;
    int cls = blk / 12, to = blk % 12;
    int rh = cls >> 2, rw = cls & 3;
    int tid = threadIdx.x;

    if (tid < 64) {
        int m16 = tid >> 2, cin = tid & 3;
        int c = m16 >> 2, rr = m16 & 3;
        int o = to * 4 + c;
        int s = (rh + 4 * (rr >> 1)) * 8 + (rw + 4 * (rr & 1));
        float a0 = 0.f, a1 = 0.f;
#pragma unroll
        for (int t = 0; t < 12; ++t) {
            int base = ((o * 12 + t) * 4 + cin) * 64 + s;
            float d = w_t[base] - w_s[base];
            a0 += d;
            a1 += (float)t * d;
        }
        W01[0][m16][cin] = a0;
        W01[1][m16][cin] = a1;
    }
    __syncthreads();

    int ks = tid >> 7, jh = (tid >> 6) & 1, L = tid & 63;
    int quad = L >> 4, m16 = L & 15;
    int c = m16 >> 2, rr = m16 & 3;
    int o = to * 4 + c;
    int s = (rh + 4 * (rr >> 1)) * 8 + (rw + 4 * (rr & 1));
    unsigned short us[4];
#pragma unroll
    for (int j4 = 0; j4 < 4; ++j4) {
        int j = jh * 4 + j4;
        int k = ks * 32 + quad * 8 + j;
        float val;
        if (k < 48) {
            val = w_s[((o * 12 + (k >> 2)) * 4 + (k & 3)) * 64 + s];
        } else if (k < 56) {
            val = W01[(k >> 2) & 1][m16][k & 3];
        } else if (k == 56) {
            val = b_s[o * 64 + s] + b_t[o * 64 + s];
        } else {
            val = 0.f;
        }
        HU hu;
        hu.h = (_Float16)val;
        us[j4] = hu.u;
    }
    uint2 pk;
    pk.x = (unsigned)us[0] | ((unsigned)us[1] << 16);
    pk.y = (unsigned)us[2] | ((unsigned)us[3] << 16);
    PWF[((size_t)(blk * 2 + ks) * 64 + L) * 2 + jh] = pk;
}

// ---- main: grid 512 = 32 b x 4 rh x 2 wh x 2 toh; 512 threads (8 waves).
__global__ __launch_bounds__(512, 4) void dlinear_mfma(const float* __restrict__ x,
                                                       const float4* __restrict__ PWF,
                                                       float* __restrict__ out) {
    __shared__ __align__(16) float2 As2[512 * 17];  // 69632 B: 128B X-row + 8B pad
    int tid = threadIdx.x;
    int wv = tid >> 6, L = tid & 63;
    unsigned bx = blockIdx.x;
    int toh = bx & 1, wh = (bx >> 1) & 1, rh = (bx >> 2) & 3;
    int bb = bx >> 4;
    int rcls = wv & 3, ghalf = wv >> 2;
    int cls = rh * 4 + rcls;

    // Weight fragments for this block's 6 to — issued FIRST, in flight
    // alongside the phase-1 x loads (both wait only at their first use).
    f16x8 wf[6][2];
#pragma unroll
    for (int tt = 0; tt < 6; ++tt)
#pragma unroll
        for (int ks = 0; ks < 2; ++ks) {
            F4H8 u;
            u.f4 = PWF[((size_t)(cls * 12 + toh * 6 + tt) * 2 + ks) * 64 + L];
            wf[tt][ks] = u.h8;
        }

    // Phase 1: thread = block-local pixel p: row a=p>>5 (h=4a+rh), col cw=p&31.
    int a = tid >> 5, cw = tid & 31;
    int h = 4 * a + rh, wimg = wh * 32 + cw;
    const float4* xb = (const float4*)x + (size_t)bb * 12 * 4096 + h * 64 + wimg;

    h2 X2[32] __attribute__((aligned(16)));
    {
        float sx = 0.f, sy = 0.f, sz = 0.f, sw = 0.f;
        float4 first, last;
#pragma unroll
        for (int t = 0; t < 12; ++t) {
            float4 v = xb[t * 4096];
            if (t == 0) first = v;
            if (t == 11) last = v;
            h2 aa, bbh;
            aa[0] = (_Float16)v.x; aa[1] = (_Float16)v.y;
            bbh[0] = (_Float16)v.z; bbh[1] = (_Float16)v.w;
            X2[2 * t] = aa;
            X2[2 * t + 1] = bbh;
            sx += v.x; sy += v.y; sz += v.z; sw += v.w;
        }
        const float inv25 = 1.f / 25.f;
        float A0 = (sx + 12.f * first.x + last.x) * inv25;
        float A1 = (sy + 12.f * first.y + last.y) * inv25;
        float A2 = (sz + 12.f * first.z + last.z) * inv25;
        float A3 = (sw + 12.f * first.w + last.w) * inv25;
        float D0 = (last.x - first.x) * inv25;
        float D1 = (last.y - first.y) * inv25;
        float D2 = (last.z - first.z) * inv25;
        float D3 = (last.w - first.w) * inv25;
        h2 t0, t1, t2, t3, t4, z;
        t0[0] = (_Float16)A0; t0[1] = (_Float16)A1;
        t1[0] = (_Float16)A2; t1[1] = (_Float16)A3;
        t2[0] = (_Float16)D0; t2[1] = (_Float16)D1;
        t3[0] = (_Float16)D2; t3[1] = (_Float16)D3;
        t4[0] = (_Float16)1.f; t4[1] = (_Float16)0.f;
        z[0] = (_Float16)0.f; z[1] = (_Float16)0.f;
        X2[24] = t0; X2[25] = t1; X2[26] = t2; X2[27] = t3;
        X2[28] = t4; X2[29] = z; X2[30] = z; X2[31] = z;
    }
    {
        const float2* xf2 = (const float2*)X2;
#pragma unroll
        for (int j = 0; j < 16; ++j) As2[17 * tid + j] = xf2[j];
    }
    __syncthreads();

    // Phase 2: B-operand (pixel) fragments. Wave: class rcls, groups ghalf*4..+3.
    int quad = L >> 4, nlane = L & 15;
    f16x8 pf[4][2];
#pragma unroll
    for (int g = 0; g < 4; ++g) {
        int G = ghalf * 4 + g;
        int p = 64 * G + 32 * (nlane >> 3) + 4 * (nlane & 7) + rcls;
        int base = 17 * p;
#pragma unroll
        for (int ks = 0; ks < 2; ++ks) {
            F2H8 u;
            u.f.lo = As2[base + ks * 8 + quad * 2];
            u.f.hi = As2[base + ks * 8 + quad * 2 + 1];
            pf[g][ks] = u.h8;
        }
    }

    // Per-lane geometry for fold masks and stores.
    int rp = nlane >> 3, ci = nlane & 7;
    int wwp = wh * 8 + ci;
    bool okw0 = wwp <= 14, okw1 = wwp >= 1;  // dj=0 / dj=1
    int colf = (wh * 32 + 4 * ci + rcls) * 4 + quad;  // lane-const col+channel
    float* outb = out + (size_t)bb * 12 * 16384 + (size_t)toh * 6 * 16384;

    // Phase 3: 6 to, direct masked-fold dword stores (L2 merges across waves).
#pragma unroll
    for (int tt = 0; tt < 6; ++tt) {
#pragma unroll
        for (int g = 0; g < 4; ++g) {
            int G = ghalf * 4 + g;
            f32x4 d = {0.f, 0.f, 0.f, 0.f};
            d = __builtin_amdgcn_mfma_f32_16x16x32_f16(wf[tt][0], pf[g][0], d, 0, 0, 0);
            d = __builtin_amdgcn_mfma_f32_16x16x32_f16(wf[tt][1], pf[g][1], d, 0, 0, 0);
            int hhl = 2 * G + rp;
            bool okh0 = hhl <= 14, okh1 = hhl >= 1;
            float v = ((okh0 && okw0) ? d[0] : 0.f)
                    + ((okh0 && okw1) ? d[1] : 0.f)
                    + ((okh1 && okw0) ? d[2] : 0.f)
                    + ((okh1 && okw1) ? d[3] : 0.f);
            int h2i = 4 * hhl + rh;
            outb[(size_t)tt * 16384 + h2i * 256 + colf] = v;
        }
    }
}

extern "C" void kernel_launch(void* const* d_in, const int* in_sizes, int n_in,
                              void* d_out, int out_size, void* d_ws, size_t ws_size,
                              hipStream_t stream) {
    const float* x = (const float*)d_in[0];
    const float* w_s = (const float*)d_in[1];
    const float* b_s = (const float*)d_in[2];
    const float* w_t = (const float*)d_in[3];
    const float* b_t = (const float*)d_in[4];
    float* out = (float*)d_out;
    void* PWF = d_ws;  // 192*2*64*16 = 393216 B

    pack_frags<<<192, 256, 0, stream>>>(w_s, b_s, w_t, b_t, (uint2*)PWF);
    dlinear_mfma<<<32 * 4 * 2 * 2, 512, 0, stream>>>(x, (const float4*)PWF, out);
}